// Round 8
// baseline (318.298 us; speedup 1.0000x reference)
//
#include <hip/hip_runtime.h>
#include <hip/hip_bf16.h>

// ---------------- problem constants ----------------
constexpr int E_ = 16, K_ = 2, D_ = 1024, F_ = 512, T_ = 4096;
constexpr int TK_ = T_ * K_;          // 8192 (token,expert) slots
constexpr int CAP_ = 2048;            // per-expert capacity
constexpr int BM_ = 128;              // row alignment of expert buckets
constexpr int ROWS_MAX = 10240;       // TK + E*(BM-1) rounded up

// ---------------- workspace layout (bytes) ----------------
// Weights stored CHUNKED: W2[e][k/8][n][8] — 8-elem k-chunks, n contiguous.
constexpr size_t SZ_W   = (size_t)E_ * F_ * D_ * 2;      // one bf16 weight matrix
constexpr size_t OFF_WG2  = 0;
constexpr size_t OFF_WU2  = OFF_WG2 + SZ_W;
constexpr size_t OFF_WD2  = OFF_WU2 + SZ_W;
constexpr size_t OFF_XG   = OFF_WD2 + SZ_W;
constexpr size_t SZ_XG  = (size_t)ROWS_MAX * D_ * 2;
constexpr size_t OFF_GU   = OFF_XG + SZ_XG;              // [row][0:512]=gate, [512:1024]=up
constexpr size_t SZ_GU  = (size_t)ROWS_MAX * 1024 * 2;
constexpr size_t OFF_META = OFF_GU + SZ_GU;

typedef __attribute__((ext_vector_type(8))) short short8;
typedef __attribute__((ext_vector_type(4))) float float4v;

__device__ __forceinline__ unsigned short f2bf(float f) {
  union { float f; unsigned int u; } v; v.f = f;
  unsigned int r = (v.u + 0x7fffu + ((v.u >> 16) & 1u)) >> 16;
  return (unsigned short)r;
}
__device__ __forceinline__ float bf2f(unsigned short b) {
  union { unsigned int u; float f; } v; v.u = ((unsigned int)b) << 16;
  return v.f;
}

__device__ __forceinline__ void load_lds16(const unsigned short* g, unsigned short* l) {
  __builtin_amdgcn_global_load_lds(
      (const __attribute__((address_space(1))) unsigned int*)g,
      (__attribute__((address_space(3))) unsigned int*)l,
      16, 0, 0);
}

// ---------------- dispatch ----------------
__global__ void hist_k(const int* __restrict__ idx, int* __restrict__ cnt_raw) {
  int i = blockIdx.x * 256 + threadIdx.x;
  atomicAdd(&cnt_raw[idx[i]], 1);
}

__global__ void offsets_k(const int* __restrict__ cnt_raw, int* __restrict__ cnt_c,
                          int* __restrict__ off_al) {
  if (threadIdx.x == 0) {
    int run = 0;
    for (int e = 0; e < E_; ++e) {
      int c = cnt_raw[e]; if (c > CAP_) c = CAP_;
      cnt_c[e] = c;
      off_al[e] = run;
      run += (c + BM_ - 1) & ~(BM_ - 1);
    }
  }
}

__global__ void assign_k(const int* __restrict__ idx, const float* __restrict__ tw,
                         int* __restrict__ cnt2, const int* __restrict__ off_al,
                         int* __restrict__ row_token, float* __restrict__ row_weight) {
  int i = blockIdx.x * 256 + threadIdx.x;
  int e = idx[i];
  int r = atomicAdd(&cnt2[e], 1);
  if (r < CAP_) {
    int row = off_al[e] + r;
    row_token[row] = i >> 1;
    row_weight[row] = tw[i];
  }
}

// ---------------- gather tokens -> bf16 grouped rows ----------------
__global__ void gather_k(const float* __restrict__ hidden, const int* __restrict__ row_token,
                         unsigned short* __restrict__ Xg) {
  int r = blockIdx.x;
  int tok = row_token[r];
  int c = threadIdx.x * 4;
  ushort4 o;
  if (tok >= 0) {
    float4 v = *(const float4*)(hidden + (size_t)tok * D_ + c);
    o.x = f2bf(v.x); o.y = f2bf(v.y); o.z = f2bf(v.z); o.w = f2bf(v.w);
  } else {
    o.x = 0; o.y = 0; o.z = 0; o.w = 0;
  }
  *(ushort4*)(Xg + (size_t)r * D_ + c) = o;
}

// ---------------- prep weights: [R=k][C=n] f32 -> chunked [k/8][n][8] bf16 ----------------
// Both sides coalesced, no LDS: for each k-chunk, lanes read 64 consecutive n (256B/instr),
// write one 16B chunk each (1KB/wave contiguous).
__global__ void prep_w_k(const float* __restrict__ wg, const float* __restrict__ wu,
                         const float* __restrict__ wd,
                         unsigned short* __restrict__ Wg2, unsigned short* __restrict__ Wu2,
                         unsigned short* __restrict__ Wd2) {
  int z = blockIdx.y;                 // kind*16 + e
  int kind = z >> 4, e = z & 15;
  int wid = threadIdx.x >> 6, lane = threadIdx.x & 63;
  int xb = blockIdx.x;
  if (kind < 2) {                     // gate/up: [D][F], n=f
    if (xb >= F_ / 64) return;
    const float* src = ((kind == 0) ? wg : wu) + (size_t)e * D_ * F_;
    unsigned short* dst = ((kind == 0) ? Wg2 : Wu2) + (size_t)e * D_ * F_;
    int n = xb * 64 + lane;
    for (int kc = wid; kc < D_ / 8; kc += 4) {
      unsigned short hv[8];
#pragma unroll
      for (int j = 0; j < 8; ++j) hv[j] = f2bf(src[(size_t)(kc * 8 + j) * F_ + n]);
      *(short8*)(dst + ((size_t)kc * F_ + n) * 8) = *(short8*)hv;
    }
  } else {                            // down: [F][D], n=d
    const float* src = wd + (size_t)e * F_ * D_;
    unsigned short* dst = Wd2 + (size_t)e * F_ * D_;
    int n = xb * 64 + lane;
    for (int kc = wid; kc < F_ / 8; kc += 4) {
      unsigned short hv[8];
#pragma unroll
      for (int j = 0; j < 8; ++j) hv[j] = f2bf(src[(size_t)(kc * 8 + j) * D_ + n]);
      *(short8*)(dst + ((size_t)kc * D_ + n) * 8) = *(short8*)hv;
    }
  }
}

// LDS layouts: A = row-major with xor swizzle (slot sl of row holds chunk sl^(row&7));
// B = chunk-major [chunk][n]: fragment reads are 2-way bank-aliased (free, m136),
// and staging is perfectly coalesced (consecutive lanes -> consecutive 16B).

// ---------------- GEMM1: GU[:, kind*512+fb ..] = Xg @ W{g,u} (plain, split-matrix) ----------------
// grid x = 16 (kind = x>>3, f-block = (x&7)*64), 64x64 tile, BK=64, 4 waves 2x2, LDS 16KB
__launch_bounds__(256)
__global__ void gemm1_k(const unsigned short* __restrict__ Xg,
                        const unsigned short* __restrict__ Wg2,
                        const unsigned short* __restrict__ Wu2,
                        unsigned short* __restrict__ GU,
                        const int* __restrict__ cnt_c, const int* __restrict__ off_al) {
  int e = blockIdx.z, mt = blockIdx.y, nt = blockIdx.x;
  int cnt = cnt_c[e];
  if (mt * 64 >= cnt) return;
  int kind = nt >> 3, fb = (nt & 7) * 64;
  int rbase = off_al[e] + mt * 64;

  __shared__ unsigned short lA[64 * 64];
  __shared__ unsigned short lB[64 * 64];

  int tid = threadIdx.x, wid = tid >> 6, lane = tid & 63;
  int wm = wid >> 1, wn = wid & 1;
  int quad = lane >> 4, l15 = lane & 15;
  int sw = l15 & 7;

  const unsigned short* gB = ((kind == 0) ? Wg2 : Wu2) + (size_t)e * D_ * F_;

  float4v acc[2][2];
#pragma unroll
  for (int i = 0; i < 2; ++i)
#pragma unroll
    for (int j = 0; j < 2; ++j) acc[i][j] = (float4v){0.f, 0.f, 0.f, 0.f};

  for (int k0 = 0; k0 < D_; k0 += 64) {
    __syncthreads();
#pragma unroll
    for (int it = 0; it < 2; ++it) {
      int s = it * 256 + tid;
      int row = s >> 3, c8 = (s & 7) ^ (row & 7);
      load_lds16(Xg + (size_t)(rbase + row) * D_ + k0 + c8 * 8, &lA[s * 8]);
      int cb = s >> 6, f = s & 63;
      load_lds16(gB + (((size_t)(k0 >> 3) + cb) * F_ + fb + f) * 8, &lB[s * 8]);
    }
    __syncthreads();
#pragma unroll
    for (int kc = 0; kc < 2; ++kc) {
      short8 af[2], bf[2];
#pragma unroll
      for (int i = 0; i < 2; ++i) {
        int r = wm * 32 + i * 16 + l15;
        af[i] = *(const short8*)&lA[r * 64 + ((kc * 4 + quad) ^ sw) * 8];
      }
#pragma unroll
      for (int j = 0; j < 2; ++j) {
        int n = wn * 32 + j * 16 + l15;
        bf[j] = *(const short8*)&lB[(kc * 4 + quad) * 512 + n * 8];
      }
#pragma unroll
      for (int i = 0; i < 2; ++i)
#pragma unroll
        for (int j = 0; j < 2; ++j)
          acc[i][j] = __builtin_amdgcn_mfma_f32_16x16x32_bf16(af[i], bf[j], acc[i][j], 0, 0, 0);
    }
  }

  int rem = cnt - mt * 64;
#pragma unroll
  for (int i = 0; i < 2; ++i)
#pragma unroll
    for (int j = 0; j < 2; ++j)
#pragma unroll
      for (int r = 0; r < 4; ++r) {
        int row = wm * 32 + i * 16 + quad * 4 + r;
        if (row < rem) {
          int n = kind * 512 + fb + wn * 32 + j * 16 + l15;
          GU[(size_t)(rbase + row) * 1024 + n] = f2bf(acc[i][j][r]);
        }
      }
}

// ---------------- GEMM2: out[tok] += w * (silu(G)*U) @ Wd, silu fused into A-staging ----------------
// grid x = 16 (D/64), 64x64 tile, BK=64, 4 waves 2x2, LDS 16KB
__launch_bounds__(256)
__global__ void gemm2_k(const unsigned short* __restrict__ GU,
                        const unsigned short* __restrict__ Wd2,
                        float* __restrict__ out,
                        const int* __restrict__ cnt_c, const int* __restrict__ off_al,
                        const int* __restrict__ row_token, const float* __restrict__ row_weight) {
  int e = blockIdx.z, mt = blockIdx.y, nt = blockIdx.x;
  int cnt = cnt_c[e];
  if (mt * 64 >= cnt) return;
  int rbase = off_al[e] + mt * 64;
  int nb = nt * 64;

  __shared__ unsigned short lA[64 * 64];
  __shared__ unsigned short lB[64 * 64];

  int tid = threadIdx.x, wid = tid >> 6, lane = tid & 63;
  int wm = wid >> 1, wn = wid & 1;
  int quad = lane >> 4, l15 = lane & 15;
  int sw = l15 & 7;

  const unsigned short* gB = Wd2 + (size_t)e * F_ * D_;

  float4v acc[2][2];
#pragma unroll
  for (int i = 0; i < 2; ++i)
#pragma unroll
    for (int j = 0; j < 2; ++j) acc[i][j] = (float4v){0.f, 0.f, 0.f, 0.f};

  for (int k0 = 0; k0 < F_; k0 += 64) {
    __syncthreads();
#pragma unroll
    for (int it = 0; it < 2; ++it) {
      int s = it * 256 + tid;
      // A: load g,u chunks, silu*mul in fp32, ds_write (same swizzled layout as gemm1 A)
      int row = s >> 3, c8 = (s & 7) ^ (row & 7);
      const unsigned short* gp = GU + (size_t)(rbase + row) * 1024 + k0 + c8 * 8;
      short8 gg = *(const short8*)gp;
      short8 uu = *(const short8*)(gp + 512);
      unsigned short hv[8];
#pragma unroll
      for (int j = 0; j < 8; ++j) {
        float g = bf2f((unsigned short)gg[j]);
        float u = bf2f((unsigned short)uu[j]);
        hv[j] = f2bf(g / (1.f + __expf(-g)) * u);
      }
      *(short8*)&lA[s * 8] = *(short8*)hv;
      // B: chunk-major staging, coalesced
      int cb = s >> 6, dcol = s & 63;
      load_lds16(gB + (((size_t)(k0 >> 3) + cb) * D_ + nb + dcol) * 8, &lB[s * 8]);
    }
    __syncthreads();
#pragma unroll
    for (int kc = 0; kc < 2; ++kc) {
      short8 af[2], bf[2];
#pragma unroll
      for (int i = 0; i < 2; ++i) {
        int r = wm * 32 + i * 16 + l15;
        af[i] = *(const short8*)&lA[r * 64 + ((kc * 4 + quad) ^ sw) * 8];
      }
#pragma unroll
      for (int j = 0; j < 2; ++j) {
        int n = wn * 32 + j * 16 + l15;
        bf[j] = *(const short8*)&lB[(kc * 4 + quad) * 512 + n * 8];
      }
#pragma unroll
      for (int i = 0; i < 2; ++i)
#pragma unroll
        for (int j = 0; j < 2; ++j)
          acc[i][j] = __builtin_amdgcn_mfma_f32_16x16x32_bf16(af[i], bf[j], acc[i][j], 0, 0, 0);
    }
  }

  int rem = cnt - mt * 64;
#pragma unroll
  for (int i = 0; i < 2; ++i)
#pragma unroll
    for (int r = 0; r < 4; ++r) {
      int row = wm * 32 + i * 16 + quad * 4 + r;
      if (row < rem) {
        int gr = rbase + row;
        int tok = row_token[gr];
        if (tok >= 0) {
          float w = row_weight[gr];
          float* op = out + (size_t)tok * D_;
#pragma unroll
          for (int j = 0; j < 2; ++j) {
            int n = nb + wn * 32 + j * 16 + l15;
            atomicAdd(op + n, w * acc[i][j][r]);
          }
        }
      }
    }
}

// ---------------- launch ----------------
extern "C" void kernel_launch(void* const* d_in, const int* in_sizes, int n_in,
                              void* d_out, int out_size, void* d_ws, size_t ws_size,
                              hipStream_t stream) {
  const float* hidden  = (const float*)d_in[0];
  const int*   topkidx = (const int*)d_in[1];
  const float* topkw   = (const float*)d_in[2];
  const float* w_gate  = (const float*)d_in[3];
  const float* w_up    = (const float*)d_in[4];
  const float* w_down  = (const float*)d_in[5];
  float* out = (float*)d_out;

  char* ws = (char*)d_ws;
  unsigned short* Wg2 = (unsigned short*)(ws + OFF_WG2);
  unsigned short* Wu2 = (unsigned short*)(ws + OFF_WU2);
  unsigned short* Wd2 = (unsigned short*)(ws + OFF_WD2);
  unsigned short* Xg  = (unsigned short*)(ws + OFF_XG);
  unsigned short* GU  = (unsigned short*)(ws + OFF_GU);
  int* meta           = (int*)(ws + OFF_META);
  int* cnt_raw   = meta;
  int* cnt2      = meta + 16;
  int* cnt_c     = meta + 32;
  int* off_al    = meta + 48;
  int* row_token = meta + 64;
  float* row_weight = (float*)(meta + 64 + ROWS_MAX);

  hipMemsetAsync(out, 0, (size_t)out_size * sizeof(float), stream);
  hipMemsetAsync(meta, 0, 64 * sizeof(int), stream);
  hipMemsetAsync(row_token, 0xFF, (size_t)ROWS_MAX * sizeof(int), stream);

  hist_k<<<TK_ / 256, 256, 0, stream>>>(topkidx, cnt_raw);
  offsets_k<<<1, 64, 0, stream>>>(cnt_raw, cnt_c, off_al);
  assign_k<<<TK_ / 256, 256, 0, stream>>>(topkidx, topkw, cnt2, off_al, row_token, row_weight);

  prep_w_k<<<dim3(D_ / 64, 48), 256, 0, stream>>>(w_gate, w_up, w_down, Wg2, Wu2, Wd2);
  gather_k<<<ROWS_MAX, 256, 0, stream>>>(hidden, row_token, Xg);

  gemm1_k<<<dim3(16, CAP_ / 64, E_), 256, 0, stream>>>(Xg, Wg2, Wu2, GU, cnt_c, off_al);
  gemm2_k<<<dim3(D_ / 64, CAP_ / 64, E_), 256, 0, stream>>>(GU, Wd2, out, cnt_c, off_al,
                                                            row_token, row_weight);
}

// Round 9
// 299.363 us; speedup vs baseline: 1.0632x; 1.0632x over previous
//
#include <hip/hip_runtime.h>
#include <hip/hip_bf16.h>

// ---------------- problem constants ----------------
constexpr int E_ = 16, K_ = 2, D_ = 1024, F_ = 512, T_ = 4096;
constexpr int TK_ = T_ * K_;          // 8192 (token,expert) slots
constexpr int CAP_ = 2048;            // per-expert capacity
constexpr int BM_ = 128;              // row alignment of expert buckets
constexpr int ROWS_MAX = 10240;       // TK + E*(BM-1) rounded up

// ---------------- workspace layout (bytes) ----------------
// Weights stored CHUNKED: W2[e][k/8][n][8] — 8-elem k-chunks, n contiguous.
constexpr size_t SZ_W   = (size_t)E_ * F_ * D_ * 2;      // one bf16 weight matrix
constexpr size_t OFF_WG2  = 0;
constexpr size_t OFF_WU2  = OFF_WG2 + SZ_W;
constexpr size_t OFF_WD2  = OFF_WU2 + SZ_W;
constexpr size_t OFF_XG   = OFF_WD2 + SZ_W;
constexpr size_t SZ_XG  = (size_t)ROWS_MAX * D_ * 2;
constexpr size_t OFF_H    = OFF_XG + SZ_XG;              // H = silu(G)*U, [row][512] bf16
constexpr size_t SZ_H   = (size_t)ROWS_MAX * F_ * 2;
constexpr size_t OFF_META = OFF_H + SZ_H;

typedef __attribute__((ext_vector_type(8))) short short8;
typedef __attribute__((ext_vector_type(4))) float float4v;

__device__ __forceinline__ unsigned short f2bf(float f) {
  union { float f; unsigned int u; } v; v.f = f;
  unsigned int r = (v.u + 0x7fffu + ((v.u >> 16) & 1u)) >> 16;
  return (unsigned short)r;
}

__device__ __forceinline__ void load_lds16(const unsigned short* g, unsigned short* l) {
  __builtin_amdgcn_global_load_lds(
      (const __attribute__((address_space(1))) unsigned int*)g,
      (__attribute__((address_space(3))) unsigned int*)l,
      16, 0, 0);
}

// ---------------- dispatch ----------------
__global__ void hist_k(const int* __restrict__ idx, int* __restrict__ cnt_raw) {
  int i = blockIdx.x * 256 + threadIdx.x;
  atomicAdd(&cnt_raw[idx[i]], 1);
}

__global__ void offsets_k(const int* __restrict__ cnt_raw, int* __restrict__ cnt_c,
                          int* __restrict__ off_al) {
  if (threadIdx.x == 0) {
    int run = 0;
    for (int e = 0; e < E_; ++e) {
      int c = cnt_raw[e]; if (c > CAP_) c = CAP_;
      cnt_c[e] = c;
      off_al[e] = run;
      run += (c + BM_ - 1) & ~(BM_ - 1);
    }
  }
}

__global__ void assign_k(const int* __restrict__ idx, const float* __restrict__ tw,
                         int* __restrict__ cnt2, const int* __restrict__ off_al,
                         int* __restrict__ row_token, float* __restrict__ row_weight) {
  int i = blockIdx.x * 256 + threadIdx.x;
  int e = idx[i];
  int r = atomicAdd(&cnt2[e], 1);
  if (r < CAP_) {
    int row = off_al[e] + r;
    row_token[row] = i >> 1;
    row_weight[row] = tw[i];
  }
}

// ---------------- gather tokens -> bf16 grouped rows ----------------
__global__ void gather_k(const float* __restrict__ hidden, const int* __restrict__ row_token,
                         unsigned short* __restrict__ Xg) {
  int r = blockIdx.x;
  int tok = row_token[r];
  int c = threadIdx.x * 4;
  ushort4 o;
  if (tok >= 0) {
    float4 v = *(const float4*)(hidden + (size_t)tok * D_ + c);
    o.x = f2bf(v.x); o.y = f2bf(v.y); o.z = f2bf(v.z); o.w = f2bf(v.w);
  } else {
    o.x = 0; o.y = 0; o.z = 0; o.w = 0;
  }
  *(ushort4*)(Xg + (size_t)r * D_ + c) = o;
}

// ---------------- prep weights: [k][n] f32 -> chunked [k/8][n][8] bf16 (coalesced both sides) ----
__global__ void prep_w_k(const float* __restrict__ wg, const float* __restrict__ wu,
                         const float* __restrict__ wd,
                         unsigned short* __restrict__ Wg2, unsigned short* __restrict__ Wu2,
                         unsigned short* __restrict__ Wd2) {
  int z = blockIdx.y;                 // kind*16 + e
  int kind = z >> 4, e = z & 15;
  int wid = threadIdx.x >> 6, lane = threadIdx.x & 63;
  int xb = blockIdx.x;
  if (kind < 2) {                     // gate/up: [D][F], n=f
    if (xb >= F_ / 64) return;
    const float* src = ((kind == 0) ? wg : wu) + (size_t)e * D_ * F_;
    unsigned short* dst = ((kind == 0) ? Wg2 : Wu2) + (size_t)e * D_ * F_;
    int n = xb * 64 + lane;
    for (int kc = wid; kc < D_ / 8; kc += 4) {
      unsigned short hv[8];
#pragma unroll
      for (int j = 0; j < 8; ++j) hv[j] = f2bf(src[(size_t)(kc * 8 + j) * F_ + n]);
      *(short8*)(dst + ((size_t)kc * F_ + n) * 8) = *(short8*)hv;
    }
  } else {                            // down: [F][D], n=d
    const float* src = wd + (size_t)e * F_ * D_;
    unsigned short* dst = Wd2 + (size_t)e * F_ * D_;
    int n = xb * 64 + lane;
    for (int kc = wid; kc < F_ / 8; kc += 4) {
      unsigned short hv[8];
#pragma unroll
      for (int j = 0; j < 8; ++j) hv[j] = f2bf(src[(size_t)(kc * 8 + j) * D_ + n]);
      *(short8*)(dst + ((size_t)kc * D_ + n) * 8) = *(short8*)hv;
    }
  }
}

// LDS layouts: A = row-major, xor-swizzled (slot sl of row holds chunk sl^(row&7));
// B = chunk-major [chunk][n][8]: staging fully coalesced, fragment reads measured 0-conflict.

// ---------------- GEMM1: H = silu(Xg@Wg) * (Xg@Wu), dual-acc, silu in epilogue ----------------
// 64M x 64N, BK=64, 4 waves 2x2 (wave tile 32x32 per matrix), LDS 24KB
__launch_bounds__(256)
__global__ void gemm1_k(const unsigned short* __restrict__ Xg,
                        const unsigned short* __restrict__ Wg2,
                        const unsigned short* __restrict__ Wu2,
                        unsigned short* __restrict__ H,
                        const int* __restrict__ cnt_c, const int* __restrict__ off_al) {
  int e = blockIdx.z, mt = blockIdx.y, nt = blockIdx.x;
  int cnt = cnt_c[e];
  if (mt * 64 >= cnt) return;
  int fb = nt * 64;
  int rbase = off_al[e] + mt * 64;

  __shared__ unsigned short lA[64 * 64];
  __shared__ unsigned short lBg[64 * 64];
  __shared__ unsigned short lBu[64 * 64];

  int tid = threadIdx.x, wid = tid >> 6, lane = tid & 63;
  int wm = wid >> 1, wn = wid & 1;
  int quad = lane >> 4, l15 = lane & 15;
  int sw = l15 & 7;

  const unsigned short* gBg = Wg2 + (size_t)e * D_ * F_;
  const unsigned short* gBu = Wu2 + (size_t)e * D_ * F_;

  float4v accg[2][2], accu[2][2];
#pragma unroll
  for (int i = 0; i < 2; ++i)
#pragma unroll
    for (int j = 0; j < 2; ++j) {
      accg[i][j] = (float4v){0.f, 0.f, 0.f, 0.f};
      accu[i][j] = (float4v){0.f, 0.f, 0.f, 0.f};
    }

  for (int k0 = 0; k0 < D_; k0 += 64) {
    __syncthreads();
#pragma unroll
    for (int it = 0; it < 2; ++it) {
      int s = it * 256 + tid;
      int row = s >> 3, c8 = (s & 7) ^ (row & 7);
      load_lds16(Xg + (size_t)(rbase + row) * D_ + k0 + c8 * 8, &lA[s * 8]);
      int cb = s >> 6, f = s & 63;
      size_t go = (((size_t)(k0 >> 3) + cb) * F_ + fb + f) * 8;
      load_lds16(gBg + go, &lBg[s * 8]);
      load_lds16(gBu + go, &lBu[s * 8]);
    }
    __syncthreads();
#pragma unroll
    for (int kc = 0; kc < 2; ++kc) {
      short8 af[2], bg[2], bu[2];
#pragma unroll
      for (int i = 0; i < 2; ++i) {
        int r = wm * 32 + i * 16 + l15;
        af[i] = *(const short8*)&lA[r * 64 + ((kc * 4 + quad) ^ sw) * 8];
      }
#pragma unroll
      for (int j = 0; j < 2; ++j) {
        int n = wn * 32 + j * 16 + l15;
        bg[j] = *(const short8*)&lBg[((kc * 4 + quad) * 64 + n) * 8];
        bu[j] = *(const short8*)&lBu[((kc * 4 + quad) * 64 + n) * 8];
      }
#pragma unroll
      for (int i = 0; i < 2; ++i)
#pragma unroll
        for (int j = 0; j < 2; ++j) {
          accg[i][j] = __builtin_amdgcn_mfma_f32_16x16x32_bf16(af[i], bg[j], accg[i][j], 0, 0, 0);
          accu[i][j] = __builtin_amdgcn_mfma_f32_16x16x32_bf16(af[i], bu[j], accu[i][j], 0, 0, 0);
        }
    }
  }

  int rem = cnt - mt * 64;
#pragma unroll
  for (int i = 0; i < 2; ++i)
#pragma unroll
    for (int j = 0; j < 2; ++j)
#pragma unroll
      for (int r = 0; r < 4; ++r) {
        int row = wm * 32 + i * 16 + quad * 4 + r;
        if (row < rem) {
          float g = accg[i][j][r], u = accu[i][j][r];
          float h = (g / (1.f + __expf(-g))) * u;   // silu(g)*u — once per element
          int n = fb + wn * 32 + j * 16 + l15;
          H[(size_t)(rbase + row) * F_ + n] = f2bf(h);
        }
      }
}

// ---------------- GEMM2: out[tok] += w * (H @ Wd), plain staging ----------------
// 64M x 128N, BK=64, 4 waves 2x2 (wave tile 32x64), LDS 24KB
__launch_bounds__(256)
__global__ void gemm2_k(const unsigned short* __restrict__ H,
                        const unsigned short* __restrict__ Wd2,
                        float* __restrict__ out,
                        const int* __restrict__ cnt_c, const int* __restrict__ off_al,
                        const int* __restrict__ row_token, const float* __restrict__ row_weight) {
  int e = blockIdx.z, mt = blockIdx.y, nt = blockIdx.x;
  int cnt = cnt_c[e];
  if (mt * 64 >= cnt) return;
  int rbase = off_al[e] + mt * 64;
  int nb = nt * 128;

  __shared__ unsigned short lA[64 * 64];
  __shared__ unsigned short lB[128 * 64];

  int tid = threadIdx.x, wid = tid >> 6, lane = tid & 63;
  int wm = wid >> 1, wn = wid & 1;
  int quad = lane >> 4, l15 = lane & 15;
  int sw = l15 & 7;

  const unsigned short* gB = Wd2 + (size_t)e * F_ * D_;

  float4v acc[2][4];
#pragma unroll
  for (int i = 0; i < 2; ++i)
#pragma unroll
    for (int j = 0; j < 4; ++j) acc[i][j] = (float4v){0.f, 0.f, 0.f, 0.f};

  for (int k0 = 0; k0 < F_; k0 += 64) {
    __syncthreads();
#pragma unroll
    for (int it = 0; it < 2; ++it) {          // A: 64 rows x 8 chunks, swizzled
      int s = it * 256 + tid;
      int row = s >> 3, c8 = (s & 7) ^ (row & 7);
      load_lds16(H + (size_t)(rbase + row) * F_ + k0 + c8 * 8, &lA[s * 8]);
    }
#pragma unroll
    for (int it = 0; it < 4; ++it) {          // B: 8 chunks x 128 n, chunk-major
      int s = it * 256 + tid;
      int cb = s >> 7, n = s & 127;
      load_lds16(gB + (((size_t)(k0 >> 3) + cb) * D_ + nb + n) * 8, &lB[s * 8]);
    }
    __syncthreads();
#pragma unroll
    for (int kc = 0; kc < 2; ++kc) {
      short8 af[2], bf[4];
#pragma unroll
      for (int i = 0; i < 2; ++i) {
        int r = wm * 32 + i * 16 + l15;
        af[i] = *(const short8*)&lA[r * 64 + ((kc * 4 + quad) ^ sw) * 8];
      }
#pragma unroll
      for (int j = 0; j < 4; ++j) {
        int n = wn * 64 + j * 16 + l15;
        bf[j] = *(const short8*)&lB[((kc * 4 + quad) * 128 + n) * 8];
      }
#pragma unroll
      for (int i = 0; i < 2; ++i)
#pragma unroll
        for (int j = 0; j < 4; ++j)
          acc[i][j] = __builtin_amdgcn_mfma_f32_16x16x32_bf16(af[i], bf[j], acc[i][j], 0, 0, 0);
    }
  }

  int rem = cnt - mt * 64;
#pragma unroll
  for (int i = 0; i < 2; ++i)
#pragma unroll
    for (int r = 0; r < 4; ++r) {
      int row = wm * 32 + i * 16 + quad * 4 + r;
      if (row < rem) {
        int gr = rbase + row;
        int tok = row_token[gr];
        if (tok >= 0) {
          float w = row_weight[gr];
          float* op = out + (size_t)tok * D_;
#pragma unroll
          for (int j = 0; j < 4; ++j) {
            int n = nb + wn * 64 + j * 16 + l15;
            atomicAdd(op + n, w * acc[i][j][r]);
          }
        }
      }
    }
}

// ---------------- launch ----------------
extern "C" void kernel_launch(void* const* d_in, const int* in_sizes, int n_in,
                              void* d_out, int out_size, void* d_ws, size_t ws_size,
                              hipStream_t stream) {
  const float* hidden  = (const float*)d_in[0];
  const int*   topkidx = (const int*)d_in[1];
  const float* topkw   = (const float*)d_in[2];
  const float* w_gate  = (const float*)d_in[3];
  const float* w_up    = (const float*)d_in[4];
  const float* w_down  = (const float*)d_in[5];
  float* out = (float*)d_out;

  char* ws = (char*)d_ws;
  unsigned short* Wg2 = (unsigned short*)(ws + OFF_WG2);
  unsigned short* Wu2 = (unsigned short*)(ws + OFF_WU2);
  unsigned short* Wd2 = (unsigned short*)(ws + OFF_WD2);
  unsigned short* Xg  = (unsigned short*)(ws + OFF_XG);
  unsigned short* H   = (unsigned short*)(ws + OFF_H);
  int* meta           = (int*)(ws + OFF_META);
  int* cnt_raw   = meta;
  int* cnt2      = meta + 16;
  int* cnt_c     = meta + 32;
  int* off_al    = meta + 48;
  int* row_token = meta + 64;
  float* row_weight = (float*)(meta + 64 + ROWS_MAX);

  hipMemsetAsync(out, 0, (size_t)out_size * sizeof(float), stream);
  hipMemsetAsync(meta, 0, 64 * sizeof(int), stream);
  hipMemsetAsync(row_token, 0xFF, (size_t)ROWS_MAX * sizeof(int), stream);

  hist_k<<<TK_ / 256, 256, 0, stream>>>(topkidx, cnt_raw);
  offsets_k<<<1, 64, 0, stream>>>(cnt_raw, cnt_c, off_al);
  assign_k<<<TK_ / 256, 256, 0, stream>>>(topkidx, topkw, cnt2, off_al, row_token, row_weight);

  prep_w_k<<<dim3(D_ / 64, 48), 256, 0, stream>>>(w_gate, w_up, w_down, Wg2, Wu2, Wd2);
  gather_k<<<ROWS_MAX, 256, 0, stream>>>(hidden, row_token, Xg);

  gemm1_k<<<dim3(F_ / 64, CAP_ / 64, E_), 256, 0, stream>>>(Xg, Wg2, Wu2, H, cnt_c, off_al);
  gemm2_k<<<dim3(D_ / 128, CAP_ / 64, E_), 256, 0, stream>>>(H, Wd2, out, cnt_c, off_al,
                                                             row_token, row_weight);
}